// Round 5
// baseline (1323.396 us; speedup 1.0000x reference)
//
#include <hip/hip_runtime.h>
#include <hip/hip_bf16.h>
#include <stdint.h>

#define S_DIM 2048
#define B_DIM 16
#define H2_DIM 2048
#define V_DIM 1024
#define M_DIM (S_DIM * B_DIM)   // 32768
#define K_HALF 2048
#define K_TOT 4096

typedef __attribute__((ext_vector_type(8))) short s16x8;   // 8 bf16 (4 VGPRs) MFMA frag
typedef __attribute__((ext_vector_type(4))) float f32x4;   // MFMA accumulator

// fp32 -> bf16 round-to-nearest-even (scalar, used in transposeB only)
__device__ __forceinline__ uint16_t f2bf(float f) {
    union { float f; uint32_t u; } c; c.f = f;
    uint32_t u = c.u;
    u += 0x7fffu + ((u >> 16) & 1u);
    return (uint16_t)(u >> 16);
}

// pack 2 fp32 -> 2 bf16 (round-to-nearest), 3 VALU ops: 2 adds + 1 v_perm_b32
__device__ __forceinline__ uint32_t pack_bf16_rn(float a, float b) {
    union { float f; uint32_t u; } ca, cb; ca.f = a; cb.f = b;
    uint32_t ua = ca.u + 0x8000u;
    uint32_t ub = cb.u + 0x8000u;
    return __builtin_amdgcn_perm(ub, ua, 0x07060302u);
}

__device__ __forceinline__ s16x8 pack8(float4 x, float4 y) {
    union { uint4 u; s16x8 v; } r;
    r.u = make_uint4(pack_bf16_rn(x.x, x.y), pack_bf16_rn(x.z, x.w),
                     pack_bf16_rn(y.x, y.y), pack_bf16_rn(y.z, y.w));
    return r.v;
}

__device__ __forceinline__ float fast_tanh(float x) {
    float e = __expf(2.0f * x);
    return 1.0f - 2.0f / (e + 1.0f);
}

// async global->LDS, 16B per lane. LDS dest is wave-uniform base + lane*16.
__device__ __forceinline__ void gload_lds16(const void* g, void* l) {
    __builtin_amdgcn_global_load_lds(
        (__attribute__((address_space(1))) void*)(uintptr_t)g,
        (__attribute__((address_space(3))) void*)(uint32_t)(uintptr_t)l,
        16, 0, 0);
}

// ------------- transpose+convert Ww/Wz [K][V] fp32 -> B^T [V][K] bf16 -------------
__global__ void transposeB(const float* __restrict__ Ww, const float* __restrict__ Wz,
                           uint16_t* __restrict__ B1, uint16_t* __restrict__ B2) {
    __shared__ float tile[32][33];
    const float* src = blockIdx.z ? Wz : Ww;
    uint16_t* dst = blockIdx.z ? B2 : B1;
    int k0 = blockIdx.x * 32, v0 = blockIdx.y * 32;
    int tv = threadIdx.x & 31, tk = threadIdx.x >> 5;  // tk in 0..7
#pragma unroll
    for (int r = 0; r < 4; r++) {
        int k = tk * 4 + r;
        tile[k][tv] = src[(size_t)(k0 + k) * V_DIM + v0 + tv];
    }
    __syncthreads();
#pragma unroll
    for (int r = 0; r < 4; r++) {
        int v = tk * 4 + r;
        dst[(size_t)(v0 + v) * K_HALF + k0 + tv] = f2bf(tile[tv][v]);
    }
}

// ---------------------------------- fused GEMM ----------------------------------
// 128(m) x 256(n) tile, 4 waves 2x2 (64m x 128n each). Pipeline:
//   A: per-lane DIRECT global->reg fragment loads (16B, MFMA A-layout), prefetched
//      one full K-step ahead; eager pack to bf16 at step top (vmcnt wait is free).
//      A never touches LDS -> LDS pipe is B-only (1536 cyc/window < MFMA 2480).
//   B: bf16 LDS double-buffer via async DMA, in flight across the barrier
//      (raw s_barrier + manual vmcnt(24), never 0).
// Epilogue: u[m] += sum_n tanh(C[m,n]+bias[n]) * Vw[n]
__global__ __launch_bounds__(256, 2) void gemm_kernel(
    const float* __restrict__ F1, const float* __restrict__ F2,
    const uint16_t* __restrict__ B1, const uint16_t* __restrict__ B2,
    const float* __restrict__ bw, const float* __restrict__ bz,
    const float* __restrict__ wa_p, const float* __restrict__ Vw,
    float* __restrict__ u) {
    __shared__ __align__(16) uint16_t lB[2][256 * 64];   // 2 x 32 KB double buffer

    const int tid = threadIdx.x;
    const int lane = tid & 63;
    const int wv = tid >> 6;                      // wave 0..3, 2x2 grid
    const int wm = (wv >> 1) * 64, wn = (wv & 1) * 128;
    // XCD swizzle: the 4 n-tiles of an m-tile land on the same XCD (id mod 8),
    // spaced 8 apart in dispatch order -> A K-slices stay L2/L3-warm.
    const int id = blockIdx.x;                    // grid = 1024
    const int nBase = ((id >> 3) & 3) * 256;
    const int mBase = ((id & 7) + ((id >> 5) << 3)) * 128;
    const int lr = lane >> 3;                     // B staging: row within 8-row group
    const int lc = lane & 7;                      // LDS chunk slot
    const int cg = lc ^ lr;                       // swizzled global chunk
    const int col = lane & 15, quad = lane >> 4;

    f32x4 acc[4][8] = {};
    float4 ar[4][2][2];   // A prefetch regs: [m-frag][kk][16B half], one step ahead
    s16x8 af[4][2];       // packed bf16 A fragments for the current step

    // per-lane A row element-offsets (fit in uint32; rows m = mBase+wm+i*16+col)
    uint32_t rowOff[4];
#pragma unroll
    for (int i = 0; i < 4; i++)
        rowOff[i] = (uint32_t)((mBase + wm + i * 16 + col) * K_HALF + quad * 8);

    // B staging base pointers (this thread's fixed row/chunk assignment)
    const uint16_t* bRow[2];
    {
        const size_t boff = (size_t)(nBase + wv * 64 + lr) * K_HALF + cg * 8;
        bRow[0] = B1 + boff; bRow[1] = B2 + boff;
    }

    auto loadA = [&](int kb) {
        const float* Fh = (kb < K_HALF) ? F1 : F2;
        const int kcol = kb & (K_HALF - 1);
#pragma unroll
        for (int i = 0; i < 4; i++)
#pragma unroll
            for (int kk = 0; kk < 2; kk++) {
                const float* p = Fh + rowOff[i] + kcol + kk * 32;
                ar[i][kk][0] = ((const float4*)p)[0];
                ar[i][kk][1] = ((const float4*)p)[1];
            }
    };
    auto issueB = [&](int kb, int p) {
        const uint16_t* base = bRow[kb >> 11] + (kb & (K_HALF - 1));
#pragma unroll
        for (int j = 0; j < 8; j++)
            gload_lds16(base + (size_t)(j * 8) * K_HALF, &lB[p][(wv * 64 + j * 8) * 64]);
    };

    // prologue: prefetch step 0
    loadA(0);
    issueB(0, 0);

#pragma unroll 1
    for (int s = 0; s < 64; s++) {
        const int p = s & 1;

        // eager pack: consumes last step's A prefetch (implicit wait vmcnt(8) —
        // loads are a full step old), frees ar for immediate re-issue
#pragma unroll
        for (int i = 0; i < 4; i++)
#pragma unroll
            for (int kk = 0; kk < 2; kk++)
                af[i][kk] = pack8(ar[i][kk][0], ar[i][kk][1]);

        if (s < 63) {
            const int kb2 = (s + 1) * 64;
            loadA(kb2);            // A(s+1) -> regs  (16 loads, stay in flight)
            issueB(kb2, p ^ 1);    // B(s+1) -> LDS   (8 DMA,  stay in flight)
            // barrier1: drain exactly B(s) (8 older than the 24 just issued);
            // the whole s+1 prefetch stays flying across the barrier.
            asm volatile("s_waitcnt vmcnt(24)\n\ts_barrier" ::: "memory");
        } else {
            asm volatile("s_waitcnt vmcnt(0)\n\ts_barrier" ::: "memory");
        }

        const uint16_t* lb = lB[p];
#pragma unroll
        for (int kk = 0; kk < 2; kk++) {
            const int cidx = kk * 4 + quad;
#pragma unroll
            for (int j = 0; j < 8; j++) {
                int n = wn + j * 16 + col;
                s16x8 b = *(const s16x8*)&lb[n * 64 + ((cidx ^ (n & 7)) << 3)];
#pragma unroll
                for (int i = 0; i < 4; i++)
                    acc[i][j] = __builtin_amdgcn_mfma_f32_16x16x32_bf16(af[i][kk], b, acc[i][j], 0, 0, 0);
            }
        }
        // barrier2: all waves done reading lB[p] (reads consumed by MFMA) before
        // any wave's step-s+1 DMA could target it at s+2. No vmcnt drain.
        asm volatile("s_barrier" ::: "memory");
    }

    // ---- fused epilogue: bias + tanh + Vw-dot, reduce 128 n-cols -> u[m] ----
    const float wa05 = wa_p[0] * 0.5f;
    float biasv[8], vwv[8];
#pragma unroll
    for (int j = 0; j < 8; j++) {
        int n = nBase + wn + j * 16 + col;
        biasv[j] = bw[n] + bz[n] + wa05;
        vwv[j] = Vw[n];
    }
#pragma unroll
    for (int i = 0; i < 4; i++) {
#pragma unroll
        for (int r = 0; r < 4; r++) {
            float sv = 0.f;
#pragma unroll
            for (int j = 0; j < 8; j++) {
                float xv = acc[i][j][r] + biasv[j];
                sv += fast_tanh(xv) * vwv[j];
            }
            // reduce across the 16 n-cols held by this quad group (D: col=lane&15)
            sv += __shfl_xor(sv, 8);
            sv += __shfl_xor(sv, 4);
            sv += __shfl_xor(sv, 2);
            sv += __shfl_xor(sv, 1);
            if (col == 0)
                atomicAdd(&u[mBase + wm + i * 16 + quad * 4 + r], sv);
        }
    }
}

// ------------------- softmax over S per batch, in-place on u=d_out -------------------
__global__ void softmax_kernel(float* __restrict__ u) {
    const int b = blockIdx.x;
    const int t = threadIdx.x;  // 256 threads, 8 s-values each
    __shared__ float redm[4], reds[4];
    float v[8];
    float mx = -1e30f;
#pragma unroll
    for (int k = 0; k < 8; k++) {
        v[k] = u[(size_t)(t + k * 256) * B_DIM + b];
        mx = fmaxf(mx, v[k]);
    }
#pragma unroll
    for (int off = 32; off >= 1; off >>= 1) mx = fmaxf(mx, __shfl_xor(mx, off));
    if ((t & 63) == 0) redm[t >> 6] = mx;
    __syncthreads();
    mx = fmaxf(fmaxf(redm[0], redm[1]), fmaxf(redm[2], redm[3]));
    float s = 0.f;
#pragma unroll
    for (int k = 0; k < 8; k++) {
        v[k] = __expf(v[k] - mx);
        s += v[k];
    }
#pragma unroll
    for (int off = 32; off >= 1; off >>= 1) s += __shfl_xor(s, off);
    if ((t & 63) == 0) reds[t >> 6] = s;
    __syncthreads();
    s = reds[0] + reds[1] + reds[2] + reds[3];
    float inv = 1.0f / s;
#pragma unroll
    for (int k = 0; k < 8; k++)
        u[(size_t)(t + k * 256) * B_DIM + b] = v[k] * inv;
}

extern "C" void kernel_launch(void* const* d_in, const int* in_sizes, int n_in,
                              void* d_out, int out_size, void* d_ws, size_t ws_size,
                              hipStream_t stream) {
    const float* hidden = (const float*)d_in[0];
    const float* z = (const float*)d_in[1];
    const float* Ww = (const float*)d_in[2];
    const float* bw = (const float*)d_in[3];
    const float* Wz = (const float*)d_in[4];
    const float* bz = (const float*)d_in[5];
    const float* Vw = (const float*)d_in[6];
    // d_in[7] = vb: constant shift over the softmax axis -> no effect, dropped
    const float* wa = (const float*)d_in[8];
    float* out = (float*)d_out;

    char* ws = (char*)d_ws;
    const size_t bBytes = (size_t)V_DIM * K_HALF * 2;  // 4 MiB per B matrix (bf16)
    uint16_t* wsB1 = (uint16_t*)ws;
    uint16_t* wsB2 = (uint16_t*)(ws + bBytes);

    // u lives in d_out (zero it; GEMM accumulates, softmax finishes in-place)
    hipMemsetAsync(d_out, 0, (size_t)M_DIM * sizeof(float), stream);

    transposeB<<<dim3(K_HALF / 32, V_DIM / 32, 2), 256, 0, stream>>>(Ww, Wz, wsB1, wsB2);

    gemm_kernel<<<dim3((M_DIM / 128) * (V_DIM / 256)), 256, 0, stream>>>(
        hidden, z, wsB1, wsB2, bw, bz, wa, Vw, out);

    softmax_kernel<<<B_DIM, 256, 0, stream>>>(out);
}